// Round 2
// baseline (290.853 us; speedup 1.0000x reference)
//
#include <hip/hip_runtime.h>

// EdgeMLP: f = (relu(x@W1+b1)@W2+b2) for both edge sets, then masked pairwise
// cosine similarity out[i][j] = (cls1[i]==cls2[j]) * dot(f1_hat[i], f2_hat[j]).
// Stage 1: normalized bf16 features + int labels into ws.
// Stage 2: mfma_f32_16x16x32_bf16 per 16x16 tile (K=32 == feature dim), then
//   transpose 16x64 sub-tiles through per-wave LDS so global stores are
//   per-lane dwordx4 with 256B contiguous segments (fill-style), non-temporal
//   to avoid thrashing L2 (f2b is re-read ~32x per wave from L2).

typedef __bf16 bf16x8 __attribute__((ext_vector_type(8)));
typedef float floatx4 __attribute__((ext_vector_type(4)));

__global__ __launch_bounds__(64) void mlp_norm_kernel(
    const float* __restrict__ e1, const float* __restrict__ e2,
    const float* __restrict__ W1, const float* __restrict__ b1,
    const float* __restrict__ W2, const float* __restrict__ b2,
    __bf16* __restrict__ f1b, __bf16* __restrict__ f2b,
    int* __restrict__ cls1, int* __restrict__ cls2, int N1, int N2)
{
    __shared__ float sW1[192];
    __shared__ float sb1[64];
    __shared__ float sW2[2048];
    __shared__ float sb2[32];
    for (int i = threadIdx.x; i < 192; i += 64) sW1[i] = W1[i];
    if (threadIdx.x < 64) sb1[threadIdx.x] = b1[threadIdx.x];
    for (int i = threadIdx.x; i < 2048; i += 64) sW2[i] = W2[i];
    if (threadIdx.x < 32) sb2[threadIdx.x] = b2[threadIdx.x];
    __syncthreads();

    int t = blockIdx.x * 64 + threadIdx.x;
    if (t >= N1 + N2) return;

    const float* src;
    __bf16* fout;
    int* cout;
    int row;
    if (t < N1) { row = t;      src = e1 + (size_t)row * 4; fout = f1b; cout = cls1; }
    else        { row = t - N1; src = e2 + (size_t)row * 4; fout = f2b; cout = cls2; }

    float x0 = src[0], x1 = src[1], x2 = src[2];
    int lbl = (int)src[3];

    float f[32];
#pragma unroll
    for (int k = 0; k < 32; ++k) f[k] = sb2[k];

    for (int j = 0; j < 64; ++j) {
        float h = fmaf(x0, sW1[j], fmaf(x1, sW1[64 + j], fmaf(x2, sW1[128 + j], sb1[j])));
        h = fmaxf(h, 0.0f);
#pragma unroll
        for (int k = 0; k < 32; ++k) f[k] = fmaf(h, sW2[j * 32 + k], f[k]);
    }

    float ss = 0.0f;
#pragma unroll
    for (int k = 0; k < 32; ++k) ss = fmaf(f[k], f[k], ss);
    float n = sqrtf(ss);
    float scale = (n > 1e-20f) ? (1.0f / n) : 0.0f;

    __bf16* dst = fout + (size_t)row * 32;
#pragma unroll
    for (int k = 0; k < 32; ++k) dst[k] = (__bf16)(f[k] * scale);
    cout[row] = lbl;
}

// Each wave: 16-row strip x 512-col span, processed as 8 rounds of 16x64.
// Per round: 4 MFMAs -> mask -> LDS (per-wave 16x68 fp32 buffer) -> read back
// transposed -> 4 nontemporal dwordx4 stores (16 lanes = 256B contiguous/row).
// A/B frag layout: row = lane&15, k = (lane>>4)*8+j. C/D: col=lane&15,
// row=(lane>>4)*4+reg.
__global__ __launch_bounds__(256) void pair_cos_kernel(
    const __bf16* __restrict__ f1b, const __bf16* __restrict__ f2b,
    const int* __restrict__ cls1, const int* __restrict__ cls2,
    float* __restrict__ out, int N2, int ncg)
{
    __shared__ float lds[4][16 * 68];  // 4 waves * 4352B, +4 dword row pad
    const int tid = threadIdx.x;
    const int lane = tid & 63;
    const int w = tid >> 6;
    float* wbuf = lds[w];

    const int wid = blockIdx.x * 4 + w;
    const int istrip = wid / ncg;
    const int cg = wid - istrip * ncg;
    const int i0 = istrip * 16;
    const int j0 = cg * 512;
    const int r16 = lane & 15;
    const int q = lane >> 4;

    bf16x8 a = *(const bf16x8*)(f1b + (size_t)(i0 + r16) * 32 + q * 8);
    int4 c1v = *(const int4*)(cls1 + i0 + q * 4);
    int cc[4] = {c1v.x, c1v.y, c1v.z, c1v.w};

    for (int r = 0; r < 8; ++r) {
        int jb = j0 + r * 64;
        floatx4 d[4];
        int c2[4];
#pragma unroll
        for (int t = 0; t < 4; ++t) {
            int j = jb + t * 16;
            bf16x8 b = *(const bf16x8*)(f2b + (size_t)(j + r16) * 32 + q * 8);
            c2[t] = cls2[j + r16];
            floatx4 z = {0.0f, 0.0f, 0.0f, 0.0f};
            d[t] = __builtin_amdgcn_mfma_f32_16x16x32_bf16(a, b, z, 0, 0, 0);
        }
        // masked scatter into LDS: row = q*4+m, col = t*16+r16 (2-way banks: free)
#pragma unroll
        for (int t = 0; t < 4; ++t) {
#pragma unroll
            for (int m = 0; m < 4; ++m) {
                float v = (cc[m] == c2[t]) ? d[t][m] : 0.0f;
                wbuf[(q * 4 + m) * 68 + t * 16 + r16] = v;
            }
        }
        asm volatile("s_waitcnt lgkmcnt(0)" ::: "memory");
        // read back row-major: store instr k covers rows 4k..4k+3,
        // 16 lanes x 16B = 256B contiguous per row.
#pragma unroll
        for (int k = 0; k < 4; ++k) {
            floatx4 v = *(const floatx4*)(wbuf + (4 * k + q) * 68 + r16 * 4);
            float* dst = out + (size_t)(i0 + 4 * k + q) * N2 + jb + r16 * 4;
            __builtin_nontemporal_store(v, (floatx4*)dst);
        }
        asm volatile("s_waitcnt lgkmcnt(0)" ::: "memory");
    }
}

extern "C" void kernel_launch(void* const* d_in, const int* in_sizes, int n_in,
                              void* d_out, int out_size, void* d_ws, size_t ws_size,
                              hipStream_t stream) {
    const float* e1 = (const float*)d_in[0];
    const float* e2 = (const float*)d_in[1];
    const float* W1 = (const float*)d_in[2];
    const float* b1 = (const float*)d_in[3];
    const float* W2 = (const float*)d_in[4];
    const float* b2 = (const float*)d_in[5];
    float* out = (float*)d_out;

    const int N1 = in_sizes[0] / 4;  // 8192
    const int N2 = in_sizes[1] / 4;  // 8192

    char* ws = (char*)d_ws;
    __bf16* f1b = (__bf16*)ws;                                   // N1*32 bf16
    __bf16* f2b = (__bf16*)(ws + (size_t)N1 * 64);               // N2*32 bf16
    int* cls1 = (int*)(ws + (size_t)(N1 + N2) * 64);             // N1 ints
    int* cls2 = cls1 + N1;                                       // N2 ints

    int nrows = N1 + N2;
    mlp_norm_kernel<<<(nrows + 63) / 64, 64, 0, stream>>>(
        e1, e2, W1, b1, W2, b2, f1b, f2b, cls1, cls2, N1, N2);

    int ncg = N2 / 512;                 // 16 col-groups of 512
    int nwaves = (N1 / 16) * ncg;       // 8192 waves
    pair_cos_kernel<<<nwaves / 4, 256, 0, stream>>>(
        f1b, f2b, cls1, cls2, out, N2, ncg);
}

// Round 3
// 280.362 us; speedup vs baseline: 1.0374x; 1.0374x over previous
//
#include <hip/hip_runtime.h>

// EdgeMLP: f = (relu(x@W1+b1)@W2+b2) for both edge sets, then masked pairwise
// cosine similarity out[i][j] = (cls1[i]==cls2[j]) * dot(f1_hat[i], f2_hat[j]).
// Stage 1: normalized bf16 features + int labels into ws (R1 version, known good).
// Stage 2: mfma_f32_32x32x16_bf16 x2 per 32x32 tile (K=32 split into 2 k-steps).
//   C/D layout (m74/m101): col=lane&31, row=(reg&3)+8*(reg>>2)+4*(lane>>5)
//   -> each store_dword covers two FULL 128B lines (32 lanes x 4B, contiguous
//   cols), eliminating the 64B partial-line segments of the 16x16 path.

typedef __bf16 bf16x8 __attribute__((ext_vector_type(8)));
typedef float floatx16 __attribute__((ext_vector_type(16)));

__global__ __launch_bounds__(256) void mlp_norm_kernel(
    const float* __restrict__ e1, const float* __restrict__ e2,
    const float* __restrict__ W1, const float* __restrict__ b1,
    const float* __restrict__ W2, const float* __restrict__ b2,
    __bf16* __restrict__ f1b, __bf16* __restrict__ f2b,
    int* __restrict__ cls1, int* __restrict__ cls2, int N1, int N2)
{
    __shared__ float sW1[192];
    __shared__ float sb1[64];
    __shared__ float sW2[2048];
    __shared__ float sb2[32];
    for (int i = threadIdx.x; i < 192; i += 256) sW1[i] = W1[i];
    if (threadIdx.x < 64) sb1[threadIdx.x] = b1[threadIdx.x];
    for (int i = threadIdx.x; i < 2048; i += 256) sW2[i] = W2[i];
    if (threadIdx.x < 32) sb2[threadIdx.x] = b2[threadIdx.x];
    __syncthreads();

    int t = blockIdx.x * 256 + threadIdx.x;
    if (t >= N1 + N2) return;

    const float* src;
    __bf16* fout;
    int* cout;
    int row;
    if (t < N1) { row = t;      src = e1 + (size_t)row * 4; fout = f1b; cout = cls1; }
    else        { row = t - N1; src = e2 + (size_t)row * 4; fout = f2b; cout = cls2; }

    float x0 = src[0], x1 = src[1], x2 = src[2];
    int lbl = (int)src[3];

    float f[32];
#pragma unroll
    for (int k = 0; k < 32; ++k) f[k] = sb2[k];

    for (int j = 0; j < 64; ++j) {
        float h = fmaf(x0, sW1[j], fmaf(x1, sW1[64 + j], fmaf(x2, sW1[128 + j], sb1[j])));
        h = fmaxf(h, 0.0f);
#pragma unroll
        for (int k = 0; k < 32; ++k) f[k] = fmaf(h, sW2[j * 32 + k], f[k]);
    }

    float ss = 0.0f;
#pragma unroll
    for (int k = 0; k < 32; ++k) ss = fmaf(f[k], f[k], ss);
    float n = sqrtf(ss);
    float scale = (n > 1e-20f) ? (1.0f / n) : 0.0f;

    __bf16* dst = fout + (size_t)row * 32;
#pragma unroll
    for (int k = 0; k < 32; ++k) dst[k] = (__bf16)(f[k] * scale);
    cout[row] = lbl;
}

// Each wave: one 32-row strip x 256-col span = 8 tiles of 32x32.
// Per tile: 2 MFMAs (k-halves), 16 masked dword stores; each store covers
// rows {r, r+4} x 32 consecutive cols = 2 full 128B lines.
// A/B frag layout (32x32x16): row(A)/col(B)=lane&31, k=(lane>>5)*8 + j.
__global__ __launch_bounds__(256) void pair_cos_kernel(
    const __bf16* __restrict__ f1b, const __bf16* __restrict__ f2b,
    const int* __restrict__ cls1, const int* __restrict__ cls2,
    float* __restrict__ out, int N2, int ncg)
{
    const int lane = threadIdx.x & 63;
    const int w = threadIdx.x >> 6;
    const int wid = blockIdx.x * 4 + w;
    const int istrip = wid / ncg;
    const int cg = wid - istrip * ncg;
    const int i0 = istrip * 32;
    const int j0 = cg * 256;
    const int l31 = lane & 31;
    const int hi = lane >> 5;

    // A fragments for both k-halves (k 0..15 and 16..31 of the 32-dim feature)
    const __bf16* arow = f1b + (size_t)(i0 + l31) * 32 + hi * 8;
    bf16x8 a0 = *(const bf16x8*)(arow);
    bf16x8 a1 = *(const bf16x8*)(arow + 16);

    // per-lane label for each of the 16 C-regs: row = (m) + 8*g + 4*hi
    int c1r[16];
#pragma unroll
    for (int g = 0; g < 4; ++g) {
        int4 v = *(const int4*)(cls1 + i0 + 8 * g + 4 * hi);
        c1r[g * 4 + 0] = v.x; c1r[g * 4 + 1] = v.y;
        c1r[g * 4 + 2] = v.z; c1r[g * 4 + 3] = v.w;
    }

#pragma unroll
    for (int t = 0; t < 8; ++t) {
        int j = j0 + t * 32;
        const __bf16* brow = f2b + (size_t)(j + l31) * 32 + hi * 8;
        bf16x8 b0 = *(const bf16x8*)(brow);
        bf16x8 b1 = *(const bf16x8*)(brow + 16);
        int c2v = cls2[j + l31];

        floatx16 acc = {};
        acc = __builtin_amdgcn_mfma_f32_32x32x16_bf16(a0, b0, acc, 0, 0, 0);
        acc = __builtin_amdgcn_mfma_f32_32x32x16_bf16(a1, b1, acc, 0, 0, 0);

#pragma unroll
        for (int g = 0; g < 4; ++g) {
#pragma unroll
            for (int m = 0; m < 4; ++m) {
                int reg = g * 4 + m;
                int row = m + 8 * g + 4 * hi;
                float v = (c1r[reg] == c2v) ? acc[reg] : 0.0f;
                out[(size_t)(i0 + row) * N2 + j + l31] = v;
            }
        }
    }
}

extern "C" void kernel_launch(void* const* d_in, const int* in_sizes, int n_in,
                              void* d_out, int out_size, void* d_ws, size_t ws_size,
                              hipStream_t stream) {
    const float* e1 = (const float*)d_in[0];
    const float* e2 = (const float*)d_in[1];
    const float* W1 = (const float*)d_in[2];
    const float* b1 = (const float*)d_in[3];
    const float* W2 = (const float*)d_in[4];
    const float* b2 = (const float*)d_in[5];
    float* out = (float*)d_out;

    const int N1 = in_sizes[0] / 4;  // 8192
    const int N2 = in_sizes[1] / 4;  // 8192

    char* ws = (char*)d_ws;
    __bf16* f1b = (__bf16*)ws;                                   // N1*32 bf16
    __bf16* f2b = (__bf16*)(ws + (size_t)N1 * 64);               // N2*32 bf16
    int* cls1 = (int*)(ws + (size_t)(N1 + N2) * 64);             // N1 ints
    int* cls2 = cls1 + N1;                                       // N2 ints

    int nrows = N1 + N2;
    mlp_norm_kernel<<<(nrows + 255) / 256, 256, 0, stream>>>(
        e1, e2, W1, b1, W2, b2, f1b, f2b, cls1, cls2, N1, N2);

    int ncg = N2 / 256;                 // 32 col-groups of 256
    int nwaves = (N1 / 32) * ncg;       // 8192 waves
    pair_cos_kernel<<<nwaves / 4, 256, 0, stream>>>(
        f1b, f2b, cls1, cls2, out, N2, ncg);
}